// Round 12
// baseline (173.749 us; speedup 1.0000x reference)
//
#include <hip/hip_runtime.h>
#include <hip/hip_bf16.h>
#include <stdint.h>

// Problem constants (fixed by setup_inputs)
#define PRIME 2147483647u
#define GAMMA 0.3f
#define K_HASH 128
#define S_SET 8
#define NB 4
#define LQ 1024
#define LK 1024
#define EDIM 512

typedef unsigned short ushort_t;
typedef __attribute__((ext_vector_type(8))) short short8;
typedef __attribute__((ext_vector_type(4))) float f32x4;

static __device__ __forceinline__ unsigned short f2bf(float f) {
    unsigned u = __builtin_bit_cast(unsigned, f);
    u += 0x7FFFu + ((u >> 16) & 1u);   // RNE (no NaN in this problem)
    return (unsigned short)(u >> 16);
}

// async global->LDS, 16B per lane; LDS dst must be lane-contiguous.
static __device__ __forceinline__ void glds16(const void* g, void* l) {
    __builtin_amdgcn_global_load_lds(
        (const __attribute__((address_space(1))) unsigned int*)g,
        (__attribute__((address_space(3))) unsigned int*)l, 16, 0, 0);
}

#define SWZ(r) ((((r) >> 2) & 3) ^ ((r) & 3))

// packed nonmatch accumulate: acc += per-half min(a^b,1). Forced v_pk_min_u16
// (LLVM scalarizes __builtin_elementwise_min on u16x2: R5->R6 proved 2.1x).
static __device__ __forceinline__ unsigned nm2(unsigned acc, unsigned a,
                                               unsigned b, unsigned ones) {
    unsigned x = a ^ b, t;
    asm("v_pk_min_u16 %0, %1, %2" : "=v"(t) : "v"(x), "v"(ones));
    return acc + t;                       // halves <= 64: no cross-half carry
}
static __device__ __forceinline__ unsigned nm8(unsigned acc, int4 q, int4 k,
                                               unsigned ones) {
    acc = nm2(acc, (unsigned)q.x, (unsigned)k.x, ones);
    acc = nm2(acc, (unsigned)q.y, (unsigned)k.y, ones);
    acc = nm2(acc, (unsigned)q.z, (unsigned)k.z, ones);
    acc = nm2(acc, (unsigned)q.w, (unsigned)k.w, ones);
    return acc;
}

// ---------------------------------------------------------------------------
// 64x64-tile bf16 BT-GEMM device fn: C=A@B^T (+epilogue), f32 accum,
// 4 waves x 32x32, glds width-16, XOR-swizzled LDS, double-buffered.
// ---------------------------------------------------------------------------
#define EPI_ROWBIAS  0
#define EPI_ROWDIV   1
#define EPI_COLBIAS  2

template<int OUTF32, int MODE>
static __device__ void gemm64_dev(
        const ushort_t* __restrict__ A, const ushort_t* __restrict__ B,
        void* __restrict__ C,
        const float* __restrict__ bias, const float* __restrict__ scale,
        int lda, int ldb, int ldc, int Kd, int m0, int n0,
        ushort_t* AsBase, ushort_t* BsBase, int tid) {
    ushort_t (*As)[64 * 32] = (ushort_t (*)[64 * 32])AsBase;
    ushort_t (*Bs)[64 * 32] = (ushort_t (*)[64 * 32])BsBase;
    int w = tid >> 6, lane = tid & 63;
    int wm = (w & 1) * 32, wn = (w >> 1) * 32;
    int mrow = lane & 15, kg = lane >> 4;

    int r = tid >> 2, c = (tid & 3) ^ SWZ(r);
    const ushort_t* pa = A + (size_t)(m0 + r) * lda + c * 8;
    const ushort_t* pb = B + (size_t)(n0 + r) * ldb + c * 8;

    int aoff[2], boff[2];
    #pragma unroll
    for (int s = 0; s < 2; s++) {
        int Ra = wm + s * 16 + mrow;
        aoff[s] = Ra * 32 + (kg ^ SWZ(Ra)) * 8;
        int Rb = wn + s * 16 + mrow;
        boff[s] = Rb * 32 + (kg ^ SWZ(Rb)) * 8;
    }

    f32x4 acc[2][2] = {};
    int nK = Kd >> 5;
    glds16(pa, &As[0][tid * 8]);
    glds16(pb, &Bs[0][tid * 8]);
    for (int i = 0; i < nK; i++) {
        __syncthreads();
        int cur = i & 1, nxt = cur ^ 1;
        if (i + 1 < nK) {
            int k0 = (i + 1) << 5;
            glds16(pa + k0, &As[nxt][tid * 8]);
            glds16(pb + k0, &Bs[nxt][tid * 8]);
        }
        short8 af[2], bh[2];
        #pragma unroll
        for (int s = 0; s < 2; s++) {
            af[s] = *(const short8*)&As[cur][aoff[s]];
            bh[s] = *(const short8*)&Bs[cur][boff[s]];
        }
        #pragma unroll
        for (int ii = 0; ii < 2; ii++)
            #pragma unroll
            for (int jj = 0; jj < 2; jj++)
                acc[ii][jj] = __builtin_amdgcn_mfma_f32_16x16x32_bf16(
                                  af[ii], bh[jj], acc[ii][jj], 0, 0, 0);
    }

    int col = lane & 15, rbase = (lane >> 4) * 4;
    #pragma unroll
    for (int ii = 0; ii < 2; ii++) {
        #pragma unroll
        for (int jj = 0; jj < 2; jj++) {
            #pragma unroll
            for (int rr = 0; rr < 4; rr++) {
                int gm = m0 + wm + ii * 16 + rbase + rr;
                int gn = n0 + wn + jj * 16 + col;
                float v = acc[ii][jj][rr];
                if (MODE == EPI_ROWBIAS)     v += bias[gm];
                else if (MODE == EPI_ROWDIV) v /= scale[gm];
                else                         v += bias[gn];
                size_t cix = (size_t)gm * ldc + gn;
                if (OUTF32) ((float*)C)[cix] = v;
                else        ((ushort_t*)C)[cix] = f2bf(v);
            }
        }
    }
}

// ---------------------------------------------------------------------------
// 1) prep: fused f32->bf16 convert (value/Wv/Wo) + MinHash signatures.
//    Signatures truncated to low 16 bits (FP rate 2^-16, output effect ~1e-6).
// ---------------------------------------------------------------------------
#define CVT_N0 (NB * LK * EDIM)
#define CVT_N1 (EDIM * EDIM)
#define CVT_N2 (EDIM * EDIM)
#define CVT_BLOCKS ((CVT_N0 + CVT_N1 + CVT_N2) / (256 * 8))   // 1280
#define SIG_BLOCKS (NB * (LQ + LK) / 2)                        // 4096

__global__ __launch_bounds__(256) void prep_kernel(
        const float* __restrict__ v, const float* __restrict__ wv,
        const float* __restrict__ wo,
        ushort_t* __restrict__ vb, ushort_t* __restrict__ wvb,
        ushort_t* __restrict__ wob,
        const int* __restrict__ ts_q, const int* __restrict__ ts_k,
        const int* __restrict__ ha, const int* __restrict__ hb,
        ushort_t* __restrict__ sig_q, ushort_t* __restrict__ sig_k,
        float* __restrict__ rs) {
    int blk = blockIdx.x;
    if (blk < CVT_BLOCKS) {               // ---- convert branch ----
        size_t i = ((size_t)blk * 256 + threadIdx.x) * 8;
        const float* src; ushort_t* dst; size_t off;
        if (i < CVT_N0)                { src = v;  dst = vb;  off = i; }
        else if (i < CVT_N0 + CVT_N1)  { src = wv; dst = wvb; off = i - CVT_N0; }
        else                           { src = wo; dst = wob; off = i - CVT_N0 - CVT_N1; }
        float4 a = *(const float4*)(src + off);
        float4 b = *(const float4*)(src + off + 4);
        ushort4 o0, o1;
        o0.x = f2bf(a.x); o0.y = f2bf(a.y); o0.z = f2bf(a.z); o0.w = f2bf(a.w);
        o1.x = f2bf(b.x); o1.y = f2bf(b.y); o1.z = f2bf(b.z); o1.w = f2bf(b.w);
        *(ushort4*)(dst + off)     = o0;
        *(ushort4*)(dst + off + 4) = o1;
        return;
    }
    // ---- signature branch: 2 token-sets per block ----
    int sb = blk - CVT_BLOCKS;            // 0..4095
    if (sb < 16) rs[sb * 256 + threadIdx.x] = 0.f;  // zero rowsum[4096]
    int half = threadIdx.x >> 7, k = threadIdx.x & 127;
    int row = sb * 2 + half;
    const int* ts = (row < NB * LQ) ? ts_q : ts_k;
    ushort_t* sig = (row < NB * LQ) ? sig_q : sig_k;
    int idx = row & (NB * LQ - 1);
    unsigned long long a  = (unsigned)ha[k];
    unsigned long long bb = (unsigned)hb[k];
    __shared__ int ids[2][S_SET];
    if (k < S_SET) ids[half][k] = ts[idx * S_SET + k];
    __syncthreads();
    unsigned mn = 0xFFFFFFFFu;
    #pragma unroll
    for (int s = 0; s < S_SET; s++) {
        unsigned long long x = a * (unsigned long long)(unsigned)ids[half][s] + bb;
        x = (x & PRIME) + (x >> 31);      // 2^31 == 1 (mod 2^31-1)
        x = (x & PRIME) + (x >> 31);
        unsigned r = (unsigned)x;
        if (r >= PRIME) r -= PRIME;
        mn = (r < mn) ? r : mn;
    }
    sig[idx * K_HASH + k] = (ushort_t)mn;
}

// ---------------------------------------------------------------------------
// 2) jacg1: parity-interleaved fusion of jaccard and GEMM1 (independent
//    work; m114: VALU-waves and MFMA-waves on one CU co-run at max not sum).
//    Even blocks: jaccard 128x64 tile (8x4/thread, two 8-group halves,
//    aligned pitch-36 LDS, Q-reads broadcast, K-reads 2-way=free).
//    Odd blocks: GEMM1 Vt[d,bj] = Wvb[d,:].Vb[bj,:] + bv[d].
// ---------------------------------------------------------------------------
union JacSmem {
    struct {
        int Qs[128 * 36];                 // 18 KB (pitch 9 int4, aligned)
        int Ks[64 * 36];                  // 9 KB
        float lut[K_HASH + 1];
    } jac;
    struct {
        ushort_t As[2][64 * 32];
        ushort_t Bs[2][64 * 32];
    } g;
};

__global__ __launch_bounds__(256) void jacg1_kernel(
        const ushort_t* __restrict__ sig_q, const ushort_t* __restrict__ sig_k,
        ushort_t* __restrict__ P, float* __restrict__ rs,
        const ushort_t* __restrict__ Wvb, const ushort_t* __restrict__ Vb,
        ushort_t* __restrict__ Vt, const float* __restrict__ bv) {
    __shared__ JacSmem sm;
    int blk = blockIdx.x, tid = threadIdx.x;
    if (blk & 1) {                        // ---- GEMM1 tile ----
        int t = blk >> 1;                 // 0..511: n-tiles 64, m-tiles 8
        gemm64_dev<0, EPI_ROWBIAS>(Wvb, Vb, Vt, bv, nullptr,
                                   EDIM, EDIM, NB * LK, EDIM,
                                   (t >> 6) * 64, (t & 63) * 64,
                                   sm.g.As[0], sm.g.Bs[0], tid);
        return;
    }
    // ---- jaccard 128x64 ----
    int t = blk >> 1;                     // 0..511
    if (tid <= K_HASH) {
        float r = (float)(K_HASH - tid) / (float)(K_HASH + tid); // (1-J)/(1+J)
        sm.jac.lut[tid] = expf(expf(-GAMMA * (2.0f * S_SET) * r));
    }
    int b = t >> 7;
    int q0 = ((t >> 4) & 7) * 128, j0 = (t & 15) * 64;
    const int4* gq = (const int4*)(sig_q + ((size_t)b * LQ + q0) * K_HASH);
    const int4* gk = (const int4*)(sig_k + ((size_t)b * LK + j0) * K_HASH);
    int tx = tid & 15, ty = tid >> 4;     // tx: 4 cols, ty: 8 rows per thread
    unsigned ones = 0x00010001u;
    unsigned acc[8][4] = {};
    int sra = tid >> 2, srb = 64 + sra, sg0 = (tid & 3) * 2;
    #pragma unroll 1
    for (int h = 0; h < 2; h++) {         // two halves of 8 hash-groups
        __syncthreads();                  // previous half fully consumed
        #pragma unroll
        for (int u = 0; u < 2; u++) {
            int g = sg0 + u;
            sm.jac.Qs[0] += 0;            // keep union alive (no-op)
            *(int4*)&sm.jac.Qs[sra * 36 + ((g ^ (sra >> 2)) & 7) * 4]
                = gq[sra * 16 + h * 8 + g];
            *(int4*)&sm.jac.Qs[srb * 36 + ((g ^ (srb >> 2)) & 7) * 4]
                = gq[srb * 16 + h * 8 + g];
            *(int4*)&sm.jac.Ks[sra * 36 + ((g ^ (sra >> 2)) & 7) * 4]
                = gk[sra * 16 + h * 8 + g];
        }
        __syncthreads();
        #pragma unroll
        for (int g = 0; g < 8; g++) {
            int4 qv[8], kv[4];
            #pragma unroll
            for (int i = 0; i < 8; i++) {
                int r = ty * 8 + i;
                qv[i] = *(const int4*)&sm.jac.Qs[r * 36 + ((g ^ (r >> 2)) & 7) * 4];
            }
            #pragma unroll
            for (int j = 0; j < 4; j++) {
                int r = tx * 4 + j;
                kv[j] = *(const int4*)&sm.jac.Ks[r * 36 + ((g ^ (r >> 2)) & 7) * 4];
            }
            #pragma unroll
            for (int i = 0; i < 8; i++)
                #pragma unroll
                for (int j = 0; j < 4; j++)
                    acc[i][j] = nm8(acc[i][j], qv[i], kv[j], ones);
        }
    }
    // counts -> P (bf16) + per-row partial sums
    ushort_t* Pb = P + (size_t)b * LQ * LK;
    float fsum[8];
    #pragma unroll
    for (int i = 0; i < 8; i++) {
        ushort4 o;
        unsigned n0_ = (acc[i][0] & 0xFFFFu) + (acc[i][0] >> 16);
        unsigned n1_ = (acc[i][1] & 0xFFFFu) + (acc[i][1] >> 16);
        unsigned n2_ = (acc[i][2] & 0xFFFFu) + (acc[i][2] >> 16);
        unsigned n3_ = (acc[i][3] & 0xFFFFu) + (acc[i][3] >> 16);
        float p0 = sm.jac.lut[K_HASH - n0_], p1 = sm.jac.lut[K_HASH - n1_];
        float p2 = sm.jac.lut[K_HASH - n2_], p3 = sm.jac.lut[K_HASH - n3_];
        fsum[i] = (p0 + p1) + (p2 + p3);
        o.x = f2bf(p0); o.y = f2bf(p1); o.z = f2bf(p2); o.w = f2bf(p3);
        int row = q0 + ty * 8 + i;
        *(ushort4*)&Pb[(size_t)row * LK + j0 + tx * 4] = o;
    }
    __syncthreads();                      // reuse Qs as f32 scratch [128][16]
    float* fs = (float*)&sm.jac.Qs[0];
    #pragma unroll
    for (int i = 0; i < 8; i++) fs[(ty * 8 + i) * 16 + tx] = fsum[i];
    __syncthreads();
    if (tid < 128) {
        float s = 0.f;
        #pragma unroll
        for (int tt = 0; tt < 16; tt++) s += fs[tid * 16 + tt];
        atomicAdd(&rs[(size_t)b * LQ + q0 + tid], s);
    }
}

// ---------------------------------------------------------------------------
// 3/4) standalone BT-GEMM wrapper (z-batched) for GEMM2 / GEMM3
// ---------------------------------------------------------------------------
template<int OUTF32, int MODE>
__global__ __launch_bounds__(256) void btgemm_kernel(
        const ushort_t* __restrict__ A, const ushort_t* __restrict__ B,
        void* __restrict__ C,
        const float* __restrict__ bias, const float* __restrict__ scale,
        int lda, int ldb, int ldc, int Kd,
        long long sA, long long sB, long long sC, long long sS) {
    __shared__ ushort_t As[2][64 * 32], Bs[2][64 * 32];
    int z = blockIdx.z;
    gemm64_dev<OUTF32, MODE>(
        A + (size_t)z * sA, B + (size_t)z * sB,
        (char*)C + (size_t)z * sC * (OUTF32 ? 4 : 2),
        bias, scale + (size_t)z * sS,
        lda, ldb, ldc, Kd, blockIdx.y * 64, blockIdx.x * 64,
        As[0], Bs[0], threadIdx.x);
}

// ---------------------------------------------------------------------------
extern "C" void kernel_launch(void* const* d_in, const int* in_sizes, int n_in,
                              void* d_out, int out_size, void* d_ws, size_t ws_size,
                              hipStream_t stream) {
    // inputs: 0 query 1 key 2 value 3 ts_q 4 ts_k 5 ha 6 hb 7 Wq 8 bq 9 Wk 10 bk
    //         11 Wv 12 bv 13 Wo 14 bo   (q/k projections are dead code)
    const float* value = (const float*)d_in[2];
    const int* tsq = (const int*)d_in[3];
    const int* tsk = (const int*)d_in[4];
    const int* ha  = (const int*)d_in[5];
    const int* hb  = (const int*)d_in[6];
    const float* Wv = (const float*)d_in[11];
    const float* bv = (const float*)d_in[12];
    const float* Wo = (const float*)d_in[13];
    const float* bo = (const float*)d_in[14];
    float* out = (float*)d_out;

    char* ws = (char*)d_ws;
    ushort_t* sigq   = (ushort_t*)(ws);                              // 1 MB
    ushort_t* sigk   = (ushort_t*)(ws + (1ull << 20));               // 1 MB
    ushort_t* P      = (ushort_t*)(ws + (4ull << 20));               // 8 MB
    float* rs        = (float*)(ws + (12ull << 20));                 // 16 KB
    ushort_t* Vt     = (ushort_t*)(ws + (12ull << 20) + (1ull << 16)); // 4 MB [512 x 4096]
    ushort_t* ctx    = (ushort_t*)(ws + (17ull << 20));              // 4 MB [4096 x 512]
    ushort_t* Vb     = (ushort_t*)(ws + (21ull << 20));              // 4 MB [4096 x 512]
    ushort_t* Wvb    = (ushort_t*)(ws + (25ull << 20));              // 512 KB
    ushort_t* Wob    = (ushort_t*)(ws + (25ull << 20) + (512ull << 10)); // 512 KB

    // 1) fused convert + signatures (+ zero rs)
    prep_kernel<<<CVT_BLOCKS + SIG_BLOCKS, 256, 0, stream>>>(
        value, Wv, Wo, Vb, Wvb, Wob, tsq, tsk, ha, hb, sigq, sigk, rs);

    // 2) jaccard (even blocks) || GEMM1 (odd blocks) — co-scheduled pipes
    jacg1_kernel<<<1024, 256, 0, stream>>>(sigq, sigk, P, rs, Wvb, Vb, Vt, bv);

    // 3) ctx[b*1024+q, d] = (1/rs[b,q]) * sum_j P[b,q,j]*Vt[d, b*1024+j]
    btgemm_kernel<0, EPI_ROWDIV><<<dim3(EDIM / 64, LQ / 64, NB), 256, 0, stream>>>(
        P, Vt, ctx, bv /*unused*/, rs,
        LK, NB * LK, EDIM, LK,
        (long long)LQ * LK, (long long)LK, (long long)LQ * EDIM, (long long)LQ);

    // 4) out[bq, n] = sum_e ctx[bq,e]*Wob[n,e] + bo[n]  (f32 -> d_out)
    btgemm_kernel<1, EPI_COLBIAS><<<dim3(EDIM / 64, NB * LQ / 64, 1), 256, 0, stream>>>(
        ctx, Wob, out, bo, rs /*unused*/,
        EDIM, EDIM, EDIM, EDIM, 0LL, 0LL, 0LL, 0LL);
}

// Round 13
// 154.713 us; speedup vs baseline: 1.1230x; 1.1230x over previous
//
#include <hip/hip_runtime.h>
#include <hip/hip_bf16.h>
#include <stdint.h>

// Problem constants (fixed by setup_inputs)
#define PRIME 2147483647u
#define GAMMA 0.3f
#define K_HASH 128
#define S_SET 8
#define NB 4
#define LQ 1024
#define LK 1024
#define EDIM 512

typedef unsigned short ushort_t;
typedef __attribute__((ext_vector_type(8))) short short8;
typedef __attribute__((ext_vector_type(4))) float f32x4;

static __device__ __forceinline__ unsigned short f2bf(float f) {
    unsigned u = __builtin_bit_cast(unsigned, f);
    u += 0x7FFFu + ((u >> 16) & 1u);   // RNE (no NaN in this problem)
    return (unsigned short)(u >> 16);
}

// async global->LDS, 16B per lane; LDS dst must be lane-contiguous.
static __device__ __forceinline__ void glds16(const void* g, void* l) {
    __builtin_amdgcn_global_load_lds(
        (const __attribute__((address_space(1))) unsigned int*)g,
        (__attribute__((address_space(3))) unsigned int*)l, 16, 0, 0);
}

#define SWZ(r) ((((r) >> 2) & 3) ^ ((r) & 3))

// packed nonmatch accumulate: acc += per-half min(a^b,1). Forced v_pk_min_u16
// (LLVM scalarizes __builtin_elementwise_min on u16x2: R5->R6 proved 2.1x).
static __device__ __forceinline__ unsigned nm2(unsigned acc, unsigned a,
                                               unsigned b, unsigned ones) {
    unsigned x = a ^ b, t;
    asm("v_pk_min_u16 %0, %1, %2" : "=v"(t) : "v"(x), "v"(ones));
    return acc + t;                       // halves <= 64: no cross-half carry
}
static __device__ __forceinline__ unsigned nm8(unsigned acc, int4 q, int4 k,
                                               unsigned ones) {
    acc = nm2(acc, (unsigned)q.x, (unsigned)k.x, ones);
    acc = nm2(acc, (unsigned)q.y, (unsigned)k.y, ones);
    acc = nm2(acc, (unsigned)q.z, (unsigned)k.z, ones);
    acc = nm2(acc, (unsigned)q.w, (unsigned)k.w, ones);
    return acc;
}

// ---------------------------------------------------------------------------
// 64x64-tile bf16 BT-GEMM device fn: C=A@B^T (+epilogue), f32 accum,
// 4 waves x 32x32, glds width-16, XOR-swizzled LDS, double-buffered.
// ---------------------------------------------------------------------------
#define EPI_ROWBIAS  0
#define EPI_ROWDIV   1
#define EPI_COLBIAS  2

template<int OUTF32, int MODE>
static __device__ void gemm64_dev(
        const ushort_t* __restrict__ A, const ushort_t* __restrict__ B,
        void* __restrict__ C,
        const float* __restrict__ bias, const float* __restrict__ scale,
        int lda, int ldb, int ldc, int Kd, int m0, int n0,
        ushort_t* AsBase, ushort_t* BsBase, int tid) {
    ushort_t (*As)[64 * 32] = (ushort_t (*)[64 * 32])AsBase;
    ushort_t (*Bs)[64 * 32] = (ushort_t (*)[64 * 32])BsBase;
    int w = tid >> 6, lane = tid & 63;
    int wm = (w & 1) * 32, wn = (w >> 1) * 32;
    int mrow = lane & 15, kg = lane >> 4;

    int r = tid >> 2, c = (tid & 3) ^ SWZ(r);
    const ushort_t* pa = A + (size_t)(m0 + r) * lda + c * 8;
    const ushort_t* pb = B + (size_t)(n0 + r) * ldb + c * 8;

    int aoff[2], boff[2];
    #pragma unroll
    for (int s = 0; s < 2; s++) {
        int Ra = wm + s * 16 + mrow;
        aoff[s] = Ra * 32 + (kg ^ SWZ(Ra)) * 8;
        int Rb = wn + s * 16 + mrow;
        boff[s] = Rb * 32 + (kg ^ SWZ(Rb)) * 8;
    }

    f32x4 acc[2][2] = {};
    int nK = Kd >> 5;
    glds16(pa, &As[0][tid * 8]);
    glds16(pb, &Bs[0][tid * 8]);
    for (int i = 0; i < nK; i++) {
        __syncthreads();
        int cur = i & 1, nxt = cur ^ 1;
        if (i + 1 < nK) {
            int k0 = (i + 1) << 5;
            glds16(pa + k0, &As[nxt][tid * 8]);
            glds16(pb + k0, &Bs[nxt][tid * 8]);
        }
        short8 af[2], bh[2];
        #pragma unroll
        for (int s = 0; s < 2; s++) {
            af[s] = *(const short8*)&As[cur][aoff[s]];
            bh[s] = *(const short8*)&Bs[cur][boff[s]];
        }
        #pragma unroll
        for (int ii = 0; ii < 2; ii++)
            #pragma unroll
            for (int jj = 0; jj < 2; jj++)
                acc[ii][jj] = __builtin_amdgcn_mfma_f32_16x16x32_bf16(
                                  af[ii], bh[jj], acc[ii][jj], 0, 0, 0);
    }

    int col = lane & 15, rbase = (lane >> 4) * 4;
    #pragma unroll
    for (int ii = 0; ii < 2; ii++) {
        #pragma unroll
        for (int jj = 0; jj < 2; jj++) {
            #pragma unroll
            for (int rr = 0; rr < 4; rr++) {
                int gm = m0 + wm + ii * 16 + rbase + rr;
                int gn = n0 + wn + jj * 16 + col;
                float v = acc[ii][jj][rr];
                if (MODE == EPI_ROWBIAS)     v += bias[gm];
                else if (MODE == EPI_ROWDIV) v /= scale[gm];
                else                         v += bias[gn];
                size_t cix = (size_t)gm * ldc + gn;
                if (OUTF32) ((float*)C)[cix] = v;
                else        ((ushort_t*)C)[cix] = f2bf(v);
            }
        }
    }
}

// ---------------------------------------------------------------------------
// 1) prep: fused f32->bf16 convert (value/Wv/Wo) + MinHash signatures.
//    Signatures truncated to low 16 bits (FP rate 2^-16, output effect ~1e-6).
// ---------------------------------------------------------------------------
#define CVT_N0 (NB * LK * EDIM)
#define CVT_N1 (EDIM * EDIM)
#define CVT_N2 (EDIM * EDIM)
#define CVT_BLOCKS ((CVT_N0 + CVT_N1 + CVT_N2) / (256 * 8))   // 1280
#define SIG_BLOCKS (NB * (LQ + LK) / 2)                        // 4096

__global__ __launch_bounds__(256) void prep_kernel(
        const float* __restrict__ v, const float* __restrict__ wv,
        const float* __restrict__ wo,
        ushort_t* __restrict__ vb, ushort_t* __restrict__ wvb,
        ushort_t* __restrict__ wob,
        const int* __restrict__ ts_q, const int* __restrict__ ts_k,
        const int* __restrict__ ha, const int* __restrict__ hb,
        ushort_t* __restrict__ sig_q, ushort_t* __restrict__ sig_k,
        float* __restrict__ rs) {
    int blk = blockIdx.x;
    if (blk < CVT_BLOCKS) {               // ---- convert branch ----
        size_t i = ((size_t)blk * 256 + threadIdx.x) * 8;
        const float* src; ushort_t* dst; size_t off;
        if (i < CVT_N0)                { src = v;  dst = vb;  off = i; }
        else if (i < CVT_N0 + CVT_N1)  { src = wv; dst = wvb; off = i - CVT_N0; }
        else                           { src = wo; dst = wob; off = i - CVT_N0 - CVT_N1; }
        float4 a = *(const float4*)(src + off);
        float4 b = *(const float4*)(src + off + 4);
        ushort4 o0, o1;
        o0.x = f2bf(a.x); o0.y = f2bf(a.y); o0.z = f2bf(a.z); o0.w = f2bf(a.w);
        o1.x = f2bf(b.x); o1.y = f2bf(b.y); o1.z = f2bf(b.z); o1.w = f2bf(b.w);
        *(ushort4*)(dst + off)     = o0;
        *(ushort4*)(dst + off + 4) = o1;
        return;
    }
    // ---- signature branch: 2 token-sets per block ----
    int sb = blk - CVT_BLOCKS;            // 0..4095
    if (sb < 16) rs[sb * 256 + threadIdx.x] = 0.f;  // zero rowsum[4096]
    int half = threadIdx.x >> 7, k = threadIdx.x & 127;
    int row = sb * 2 + half;
    const int* ts = (row < NB * LQ) ? ts_q : ts_k;
    ushort_t* sig = (row < NB * LQ) ? sig_q : sig_k;
    int idx = row & (NB * LQ - 1);
    unsigned long long a  = (unsigned)ha[k];
    unsigned long long bb = (unsigned)hb[k];
    __shared__ int ids[2][S_SET];
    if (k < S_SET) ids[half][k] = ts[idx * S_SET + k];
    __syncthreads();
    unsigned mn = 0xFFFFFFFFu;
    #pragma unroll
    for (int s = 0; s < S_SET; s++) {
        unsigned long long x = a * (unsigned long long)(unsigned)ids[half][s] + bb;
        x = (x & PRIME) + (x >> 31);      // 2^31 == 1 (mod 2^31-1)
        x = (x & PRIME) + (x >> 31);
        unsigned r = (unsigned)x;
        if (r >= PRIME) r -= PRIME;
        mn = (r < mn) ? r : mn;
    }
    sig[idx * K_HASH + k] = (ushort_t)mn;
}

// ---------------------------------------------------------------------------
// 2) jacg1: fusion of jaccard and GEMM1 with PERIOD-256 role grouping.
//    R12 lesson: CU identity = f(blk mod 256) on MI355X (8 XCDs x 32 CUs,
//    blk%8 -> XCD), so (blk&1) parity put SAME role on each CU (zero mixing,
//    54 us). Role = (blk>>8)&1 gives every CU 2 jaccard + 2 GEMM blocks
//    co-resident -> m114 MFMA/VALU co-scheduling.
//    Jaccard: 128x64 tile, 8x4/thread, two 8-group halves, aligned pitch-36
//    LDS, XOR placement (Q-reads broadcast, K-reads 2-way = free).
//    GEMM1: Vt[d,bj] = Wvb[d,:].Vb[bj,:] + bv[d].
// ---------------------------------------------------------------------------
union JacSmem {
    struct {
        int Qs[128 * 36];                 // 18 KB (pitch 9 int4, aligned)
        int Ks[64 * 36];                  // 9 KB
        float lut[K_HASH + 1];
    } jac;
    struct {
        ushort_t As[2][64 * 32];
        ushort_t Bs[2][64 * 32];
    } g;
};

__global__ __launch_bounds__(256) void jacg1_kernel(
        const ushort_t* __restrict__ sig_q, const ushort_t* __restrict__ sig_k,
        ushort_t* __restrict__ P, float* __restrict__ rs,
        const ushort_t* __restrict__ Wvb, const ushort_t* __restrict__ Vb,
        ushort_t* __restrict__ Vt, const float* __restrict__ bv) {
    __shared__ JacSmem sm;
    int blk = blockIdx.x, tid = threadIdx.x;
    int grp = blk >> 8;                   // 0..3: jac, gemm, jac, gemm
    int t = (grp >> 1) * 256 + (blk & 255);   // role-local tile id 0..511
    if (grp & 1) {                        // ---- GEMM1 tile ----
        gemm64_dev<0, EPI_ROWBIAS>(Wvb, Vb, Vt, bv, nullptr,
                                   EDIM, EDIM, NB * LK, EDIM,
                                   (t >> 6) * 64, (t & 63) * 64,
                                   sm.g.As[0], sm.g.Bs[0], tid);
        return;
    }
    // ---- jaccard 128x64 ----
    if (tid <= K_HASH) {
        float r = (float)(K_HASH - tid) / (float)(K_HASH + tid); // (1-J)/(1+J)
        sm.jac.lut[tid] = expf(expf(-GAMMA * (2.0f * S_SET) * r));
    }
    int b = t >> 7;
    int q0 = ((t >> 4) & 7) * 128, j0 = (t & 15) * 64;
    const int4* gq = (const int4*)(sig_q + ((size_t)b * LQ + q0) * K_HASH);
    const int4* gk = (const int4*)(sig_k + ((size_t)b * LK + j0) * K_HASH);
    int tx = tid & 15, ty = tid >> 4;     // tx: 4 cols, ty: 8 rows per thread
    unsigned ones = 0x00010001u;
    unsigned acc[8][4] = {};
    int sra = tid >> 2, srb = 64 + sra, sg0 = (tid & 3) * 2;
    #pragma unroll 1
    for (int h = 0; h < 2; h++) {         // two halves of 8 hash-groups
        __syncthreads();                  // previous half fully consumed
        #pragma unroll
        for (int u = 0; u < 2; u++) {
            int g = sg0 + u;
            *(int4*)&sm.jac.Qs[sra * 36 + ((g ^ (sra >> 2)) & 7) * 4]
                = gq[sra * 16 + h * 8 + g];
            *(int4*)&sm.jac.Qs[srb * 36 + ((g ^ (srb >> 2)) & 7) * 4]
                = gq[srb * 16 + h * 8 + g];
            *(int4*)&sm.jac.Ks[sra * 36 + ((g ^ (sra >> 2)) & 7) * 4]
                = gk[sra * 16 + h * 8 + g];
        }
        __syncthreads();
        #pragma unroll
        for (int g = 0; g < 8; g++) {
            int4 qv[8], kv[4];
            #pragma unroll
            for (int i = 0; i < 8; i++) {
                int r = ty * 8 + i;
                qv[i] = *(const int4*)&sm.jac.Qs[r * 36 + ((g ^ (r >> 2)) & 7) * 4];
            }
            #pragma unroll
            for (int j = 0; j < 4; j++) {
                int r = tx * 4 + j;
                kv[j] = *(const int4*)&sm.jac.Ks[r * 36 + ((g ^ (r >> 2)) & 7) * 4];
            }
            #pragma unroll
            for (int i = 0; i < 8; i++)
                #pragma unroll
                for (int j = 0; j < 4; j++)
                    acc[i][j] = nm8(acc[i][j], qv[i], kv[j], ones);
        }
    }
    // counts -> P (bf16) + per-row partial sums
    ushort_t* Pb = P + (size_t)b * LQ * LK;
    float fsum[8];
    #pragma unroll
    for (int i = 0; i < 8; i++) {
        ushort4 o;
        unsigned n0_ = (acc[i][0] & 0xFFFFu) + (acc[i][0] >> 16);
        unsigned n1_ = (acc[i][1] & 0xFFFFu) + (acc[i][1] >> 16);
        unsigned n2_ = (acc[i][2] & 0xFFFFu) + (acc[i][2] >> 16);
        unsigned n3_ = (acc[i][3] & 0xFFFFu) + (acc[i][3] >> 16);
        float p0 = sm.jac.lut[K_HASH - n0_], p1 = sm.jac.lut[K_HASH - n1_];
        float p2 = sm.jac.lut[K_HASH - n2_], p3 = sm.jac.lut[K_HASH - n3_];
        fsum[i] = (p0 + p1) + (p2 + p3);
        o.x = f2bf(p0); o.y = f2bf(p1); o.z = f2bf(p2); o.w = f2bf(p3);
        int row = q0 + ty * 8 + i;
        *(ushort4*)&Pb[(size_t)row * LK + j0 + tx * 4] = o;
    }
    __syncthreads();                      // reuse Qs as f32 scratch [128][16]
    float* fs = (float*)&sm.jac.Qs[0];
    #pragma unroll
    for (int i = 0; i < 8; i++) fs[(ty * 8 + i) * 16 + tx] = fsum[i];
    __syncthreads();
    if (tid < 128) {
        float s = 0.f;
        #pragma unroll
        for (int tt = 0; tt < 16; tt++) s += fs[tid * 16 + tt];
        atomicAdd(&rs[(size_t)b * LQ + q0 + tid], s);
    }
}

// ---------------------------------------------------------------------------
// 3/4) standalone BT-GEMM wrapper (z-batched) for GEMM2 / GEMM3
// ---------------------------------------------------------------------------
template<int OUTF32, int MODE>
__global__ __launch_bounds__(256) void btgemm_kernel(
        const ushort_t* __restrict__ A, const ushort_t* __restrict__ B,
        void* __restrict__ C,
        const float* __restrict__ bias, const float* __restrict__ scale,
        int lda, int ldb, int ldc, int Kd,
        long long sA, long long sB, long long sC, long long sS) {
    __shared__ ushort_t As[2][64 * 32], Bs[2][64 * 32];
    int z = blockIdx.z;
    gemm64_dev<OUTF32, MODE>(
        A + (size_t)z * sA, B + (size_t)z * sB,
        (char*)C + (size_t)z * sC * (OUTF32 ? 4 : 2),
        bias, scale + (size_t)z * sS,
        lda, ldb, ldc, Kd, blockIdx.y * 64, blockIdx.x * 64,
        As[0], Bs[0], threadIdx.x);
}

// ---------------------------------------------------------------------------
extern "C" void kernel_launch(void* const* d_in, const int* in_sizes, int n_in,
                              void* d_out, int out_size, void* d_ws, size_t ws_size,
                              hipStream_t stream) {
    // inputs: 0 query 1 key 2 value 3 ts_q 4 ts_k 5 ha 6 hb 7 Wq 8 bq 9 Wk 10 bk
    //         11 Wv 12 bv 13 Wo 14 bo   (q/k projections are dead code)
    const float* value = (const float*)d_in[2];
    const int* tsq = (const int*)d_in[3];
    const int* tsk = (const int*)d_in[4];
    const int* ha  = (const int*)d_in[5];
    const int* hb  = (const int*)d_in[6];
    const float* Wv = (const float*)d_in[11];
    const float* bv = (const float*)d_in[12];
    const float* Wo = (const float*)d_in[13];
    const float* bo = (const float*)d_in[14];
    float* out = (float*)d_out;

    char* ws = (char*)d_ws;
    ushort_t* sigq   = (ushort_t*)(ws);                              // 1 MB
    ushort_t* sigk   = (ushort_t*)(ws + (1ull << 20));               // 1 MB
    ushort_t* P      = (ushort_t*)(ws + (4ull << 20));               // 8 MB
    float* rs        = (float*)(ws + (12ull << 20));                 // 16 KB
    ushort_t* Vt     = (ushort_t*)(ws + (12ull << 20) + (1ull << 16)); // 4 MB [512 x 4096]
    ushort_t* ctx    = (ushort_t*)(ws + (17ull << 20));              // 4 MB [4096 x 512]
    ushort_t* Vb     = (ushort_t*)(ws + (21ull << 20));              // 4 MB [4096 x 512]
    ushort_t* Wvb    = (ushort_t*)(ws + (25ull << 20));              // 512 KB
    ushort_t* Wob    = (ushort_t*)(ws + (25ull << 20) + (512ull << 10)); // 512 KB

    // 1) fused convert + signatures (+ zero rs)
    prep_kernel<<<CVT_BLOCKS + SIG_BLOCKS, 256, 0, stream>>>(
        value, Wv, Wo, Vb, Wvb, Wob, tsq, tsk, ha, hb, sigq, sigk, rs);

    // 2) jaccard || GEMM1, period-256 role groups -> 2+2 blocks per CU
    jacg1_kernel<<<1024, 256, 0, stream>>>(sigq, sigk, P, rs, Wvb, Vb, Vt, bv);

    // 3) ctx[b*1024+q, d] = (1/rs[b,q]) * sum_j P[b,q,j]*Vt[d, b*1024+j]
    btgemm_kernel<0, EPI_ROWDIV><<<dim3(EDIM / 64, LQ / 64, NB), 256, 0, stream>>>(
        P, Vt, ctx, bv /*unused*/, rs,
        LK, NB * LK, EDIM, LK,
        (long long)LQ * LK, (long long)LK, (long long)LQ * EDIM, (long long)LQ);

    // 4) out[bq, n] = sum_e ctx[bq,e]*Wob[n,e] + bo[n]  (f32 -> d_out)
    btgemm_kernel<1, EPI_COLBIAS><<<dim3(EDIM / 64, NB * LQ / 64, 1), 256, 0, stream>>>(
        ctx, Wob, out, bo, rs /*unused*/,
        EDIM, EDIM, EDIM, EDIM, 0LL, 0LL, 0LL, 0LL);
}